// Round 3
// baseline (61.406 us; speedup 1.0000x reference)
//
#include <hip/hip_runtime.h>

typedef float v2f __attribute__((ext_vector_type(2)));

constexpr int IN_DIM = 21;
constexpr int HID = 5;
constexpr int BLK = 256;
constexpr int EPB = 2 * BLK;            // 512 elements per block
constexpr float LOG2E = 1.44269504088896340736f;

__device__ __forceinline__ v2f splat(float s) { v2f r; r.x = s; r.y = s; return r; }
__device__ __forceinline__ v2f vfma(v2f a, v2f b, v2f c) {
    return __builtin_elementwise_fma(a, b, c);
}
__device__ __forceinline__ v2f vexp2(v2f x) {
    v2f r; r.x = __builtin_amdgcn_exp2f(x.x); r.y = __builtin_amdgcn_exp2f(x.y); return r;
}
__device__ __forceinline__ v2f vrcp(v2f x) {
    v2f r; r.x = __builtin_amdgcn_rcpf(x.x); r.y = __builtin_amdgcn_rcpf(x.y); return r;
}
__device__ __forceinline__ v2f sigmoid2(v2f x) {          // 1/(1+e^-x)
    v2f t = vexp2(x * splat(-LOG2E));
    return vrcp(t + splat(1.0f));
}
__device__ __forceinline__ v2f tanh2(v2f x) {             // 1 - 2/(e^2x+1)
    v2f t = vexp2(x * splat(2.0f * LOG2E));
    v2f r = vrcp(t + splat(1.0f));
    return vfma(splat(-2.0f), r, splat(1.0f));
}

// load 10 contiguous floats (2 elems x HID) as float2s; dup=1: tail, replicate elem0
__device__ __forceinline__ void load10(const float* __restrict__ p, int dup, float* w) {
    if (!dup) {
        const v2f* p2 = (const v2f*)p;                    // 8B-aligned (e0 even)
        v2f a = p2[0], b = p2[1], c = p2[2], d = p2[3], e = p2[4];
        w[0]=a.x; w[1]=a.y; w[2]=b.x; w[3]=b.y; w[4]=c.x;
        w[5]=c.y; w[6]=d.x; w[7]=d.y; w[8]=e.x; w[9]=e.y;
    } else {
#pragma unroll
        for (int k = 0; k < HID; ++k) { w[k] = p[k]; w[HID + k] = p[k]; }
    }
}

__global__ __launch_bounds__(BLK) void lstm2_head_pk(
    const float* __restrict__ x,
    const float* __restrict__ h0,
    const float* __restrict__ c0,
    const float* __restrict__ Wih0,
    const float* __restrict__ Whh0,
    const float* __restrict__ bih0,
    const float* __restrict__ bhh0,
    const float* __restrict__ Wih1,
    const float* __restrict__ Whh1,
    const float* __restrict__ bih1,
    const float* __restrict__ bhh1,
    const float* __restrict__ Wlin,
    const float* __restrict__ blin,
    float* __restrict__ out,
    int B)
{
    __shared__ float xs[EPB * IN_DIM];                    // 43008 B

    const int base = blockIdx.x * EPB;
    // ---- coalesced float4 stage of the x tile ----
    {
        const int nrow = (B - base) < EPB ? (B - base) : EPB;
        const int nf = nrow * IN_DIM;
        const float* src = x + (size_t)base * IN_DIM;     // 16B-aligned: 43008*blockIdx
        const int n4 = nf >> 2;
        for (int i = threadIdx.x; i < n4; i += BLK)
            ((float4*)xs)[i] = ((const float4*)src)[i];
        for (int i = (n4 << 2) + threadIdx.x; i < nf; i += BLK)
            xs[i] = src[i];
    }
    __syncthreads();

    const int t = threadIdx.x;
    const int e0 = base + 2 * t;
    if (e0 >= B) return;
    const int eb = (e0 + 1 < B) ? 1 : 0;

    // ---- x fragments from LDS (stride-21 words; gcd(21,32)=1) ----
    v2f xv[IN_DIM];
    {
        const float* xl = xs + 42 * t;
#pragma unroll
        for (int j = 0; j < IN_DIM; ++j) {
            xv[j].x = xl[j];
            xv[j].y = xl[j + IN_DIM * eb];
        }
    }

    // ---- layer 0 state (vectorized contiguous loads) ----
    float wh[10], wc[10];
    load10(h0 + e0 * HID, !eb, wh);
    load10(c0 + e0 * HID, !eb, wc);
    v2f hv[HID], cv[HID];
#pragma unroll
    for (int k = 0; k < HID; ++k) {
        hv[k].x = wh[k]; hv[k].y = wh[HID + k];
        cv[k].x = wc[k]; cv[k].y = wc[HID + k];
    }

    // ---- layer 0 ----
    v2f h1[HID];
#pragma unroll
    for (int k = 0; k < HID; ++k) {
        v2f ai = splat(bih0[k]         + bhh0[k]);
        v2f af = splat(bih0[HID + k]   + bhh0[HID + k]);
        v2f ag = splat(bih0[2*HID + k] + bhh0[2*HID + k]);
        v2f ao = splat(bih0[3*HID + k] + bhh0[3*HID + k]);
#pragma unroll
        for (int j = 0; j < IN_DIM; ++j) {
            ai = vfma(splat(Wih0[(k)*IN_DIM + j]),         xv[j], ai);
            af = vfma(splat(Wih0[(HID + k)*IN_DIM + j]),   xv[j], af);
            ag = vfma(splat(Wih0[(2*HID + k)*IN_DIM + j]), xv[j], ag);
            ao = vfma(splat(Wih0[(3*HID + k)*IN_DIM + j]), xv[j], ao);
        }
#pragma unroll
        for (int kk = 0; kk < HID; ++kk) {
            ai = vfma(splat(Whh0[(k)*HID + kk]),         hv[kk], ai);
            af = vfma(splat(Whh0[(HID + k)*HID + kk]),   hv[kk], af);
            ag = vfma(splat(Whh0[(2*HID + k)*HID + kk]), hv[kk], ag);
            ao = vfma(splat(Whh0[(3*HID + k)*HID + kk]), hv[kk], ao);
        }
        v2f ig = sigmoid2(ai);
        v2f fg = sigmoid2(af);
        v2f gg = tanh2(ag);
        v2f og = sigmoid2(ao);
        v2f cn = vfma(fg, cv[k], ig * gg);
        h1[k] = og * tanh2(cn);
    }

    // ---- layer 1 state ----
    const int off1 = B * HID;
    load10(h0 + off1 + e0 * HID, !eb, wh);
    load10(c0 + off1 + e0 * HID, !eb, wc);
#pragma unroll
    for (int k = 0; k < HID; ++k) {
        hv[k].x = wh[k]; hv[k].y = wh[HID + k];
        cv[k].x = wc[k]; cv[k].y = wc[HID + k];
    }

    // ---- layer 1 ----
    v2f h2[HID];
#pragma unroll
    for (int k = 0; k < HID; ++k) {
        v2f ai = splat(bih1[k]         + bhh1[k]);
        v2f af = splat(bih1[HID + k]   + bhh1[HID + k]);
        v2f ag = splat(bih1[2*HID + k] + bhh1[2*HID + k]);
        v2f ao = splat(bih1[3*HID + k] + bhh1[3*HID + k]);
#pragma unroll
        for (int j = 0; j < HID; ++j) {
            ai = vfma(splat(Wih1[(k)*HID + j]),         h1[j], ai);
            af = vfma(splat(Wih1[(HID + k)*HID + j]),   h1[j], af);
            ag = vfma(splat(Wih1[(2*HID + k)*HID + j]), h1[j], ag);
            ao = vfma(splat(Wih1[(3*HID + k)*HID + j]), h1[j], ao);
        }
#pragma unroll
        for (int kk = 0; kk < HID; ++kk) {
            ai = vfma(splat(Whh1[(k)*HID + kk]),         hv[kk], ai);
            af = vfma(splat(Whh1[(HID + k)*HID + kk]),   hv[kk], af);
            ag = vfma(splat(Whh1[(2*HID + k)*HID + kk]), hv[kk], ag);
            ao = vfma(splat(Whh1[(3*HID + k)*HID + kk]), hv[kk], ao);
        }
        v2f ig = sigmoid2(ai);
        v2f fg = sigmoid2(af);
        v2f gg = tanh2(ag);
        v2f og = sigmoid2(ao);
        v2f cn = vfma(fg, cv[k], ig * gg);
        h2[k] = og * tanh2(cn);
    }

    // ---- head ----
    v2f o = splat(blin[0]);
#pragma unroll
    for (int k = 0; k < HID; ++k) o = vfma(splat(Wlin[k]), h2[k], o);
    v2f r = tanh2(o);

    if (eb) {
        *(v2f*)(out + e0) = r;                            // e0 even -> 8B aligned
    } else {
        out[e0] = r.x;
    }
}

extern "C" void kernel_launch(void* const* d_in, const int* in_sizes, int n_in,
                              void* d_out, int out_size, void* d_ws, size_t ws_size,
                              hipStream_t stream) {
    const float* x    = (const float*)d_in[0];
    const float* h0   = (const float*)d_in[1];
    const float* c0   = (const float*)d_in[2];
    const float* Wih0 = (const float*)d_in[3];
    const float* Whh0 = (const float*)d_in[4];
    const float* bih0 = (const float*)d_in[5];
    const float* bhh0 = (const float*)d_in[6];
    const float* Wih1 = (const float*)d_in[7];
    const float* Whh1 = (const float*)d_in[8];
    const float* bih1 = (const float*)d_in[9];
    const float* bhh1 = (const float*)d_in[10];
    const float* Wlin = (const float*)d_in[11];
    const float* blin = (const float*)d_in[12];
    float* out = (float*)d_out;

    const int B = in_sizes[0] / IN_DIM;
    const int grid = (B + EPB - 1) / EPB;
    lstm2_head_pk<<<grid, BLK, 0, stream>>>(
        x, h0, c0, Wih0, Whh0, bih0, bhh0, Wih1, Whh1, bih1, bhh1,
        Wlin, blin, out, B);
}